// Round 7
// baseline (301.135 us; speedup 1.0000x reference)
//
#include <hip/hip_runtime.h>
#include <math.h>

#define NIN 91392        // 17*21*16*16
#define DIN 8
#define DOUT 16
#define BATCH 16
#define NCHUNK (NIN / 8) // 11424 chunks of 8 n
#define NSLICE 1428      // blocks; each owns 8 chunks: 1428*8 = 11424
#define KCH 8            // chunks per block
#define TPB 256

// Pass kernel: recompute u_hat[j,n,o] = sum_i x[b,n,i]*W[j,n,i,o] on the fly.
// Thread t = (g:3)(j:1)(o:4); block = slice; all 16 batches per block.
// x for all 8 chunks staged in LDS up front (32 KB); W double-buffered in regs.
// PASS 0: s0 partial = sum_n u (c=0.5 folded into reduce)
// PASS>0: d via 32-lane butterfly, c = sigmoid(sgn*d), s partial
template<int PASS>
__global__ __launch_bounds__(TPB, 4) void caps_pass(
    const float* __restrict__ x, const float* __restrict__ W,
    const float* __restrict__ vin, float* __restrict__ part)
{
    const int t = threadIdx.x;
    const int o = t & 15;          // output dim
    const int j = (t >> 4) & 1;    // capsule
    const int g = t >> 5;          // n-subgroup 0..7
    const int slice = blockIdx.x;

    const float sgn = j ? -1.f : 1.f;

    // xs layout: [k][b][g*8+i] flat floats; 8*16*64 = 8192 floats = 32 KB
    __shared__ float xs[KCH * BATCH * 64];

    // stage x: 2048 float4s, 8 per thread, coalesced 256B runs per (k,b)
    #pragma unroll
    for (int r = 0; r < 8; ++r) {
        const int q = r * 256 + t;        // float4 index
        const int k = q >> 8;             // chunk 0..7
        const int b = (q >> 4) & 15;      // batch
        const int pos = q & 15;           // float4 within 64-float run
        const size_t gaddr = (size_t)b * (NIN * DIN)
                           + (size_t)(slice + k * NSLICE) * (8 * DIN) + pos * 4;
        *(float4*)(xs + (size_t)q * 4) = *(const float4*)(x + gaddr);
    }

    float vinreg[BATCH];
    if (PASS > 0) {
        #pragma unroll
        for (int b = 0; b < BATCH; ++b)
            vinreg[b] = sgn * vin[b * 32 + (t & 31)];
    }

    float acc[BATCH];
    #pragma unroll
    for (int b = 0; b < BATCH; ++b) acc[b] = 0.f;

    // W base for chunk k (per-thread): W[j][n(k)][i][o], i-stride 16 floats
    // prefetch chunk 0 into Wc
    float Wc[DIN], Wn[DIN];
    {
        const float* wp = W + ((size_t)j * NIN + (size_t)slice * 8 + g) * (DIN * DOUT) + o;
        #pragma unroll
        for (int i = 0; i < DIN; ++i) Wc[i] = wp[i * DOUT];
    }

    __syncthreads();   // xs ready

    #pragma unroll
    for (int k = 0; k < KCH; ++k) {
        // prefetch next chunk's W while computing this one
        if (k < KCH - 1) {
            const float* wp = W + ((size_t)j * NIN
                            + (size_t)(slice + (k + 1) * NSLICE) * 8 + g) * (DIN * DOUT) + o;
            #pragma unroll
            for (int i = 0; i < DIN; ++i) Wn[i] = wp[i * DOUT];
        }

        const float* xk = xs + (size_t)k * (BATCH * 64) + g * 8;
        #pragma unroll
        for (int b = 0; b < BATCH; ++b) {
            const float4 xa = *(const float4*)(xk + b * 64);
            const float4 xb = *(const float4*)(xk + b * 64 + 4);
            float u = xa.x*Wc[0] + xa.y*Wc[1] + xa.z*Wc[2] + xa.w*Wc[3]
                    + xb.x*Wc[4] + xb.y*Wc[5] + xb.z*Wc[6] + xb.w*Wc[7];
            if (PASS == 0) {
                acc[b] += u;
            } else {
                float m = vinreg[b] * u;           // sgn folded in
                m += __shfl_xor(m, 1);
                m += __shfl_xor(m, 2);
                m += __shfl_xor(m, 4);
                m += __shfl_xor(m, 8);
                m += __shfl_xor(m, 16);            // 32-lane (j,o) reduce
                const float cc = __builtin_amdgcn_rcpf(1.f + __expf(-sgn * m));
                acc[b] += cc * u;
            }
        }

        if (k < KCH - 1) {
            #pragma unroll
            for (int i = 0; i < DIN; ++i) Wc[i] = Wn[i];
        }
    }

    // fold the two 32-lane halves of each wave
    #pragma unroll
    for (int b = 0; b < BATCH; ++b) acc[b] += __shfl_xor(acc[b], 32);

    // cross-wave reduce, reusing xs (stride 17 -> conflict-free)
    __syncthreads();
    float* red = xs;   // [ (wave*32+lane) * 17 + b ], 128*17 = 2176 floats
    const int wave = t >> 6;
    const int lane = t & 63;
    if (lane < 32) {
        #pragma unroll
        for (int b = 0; b < BATCH; ++b) red[(wave * 32 + lane) * 17 + b] = acc[b];
    }
    __syncthreads();
    if (t < 32) {
        #pragma unroll
        for (int b = 0; b < BATCH; ++b) {
            float s = red[(0 * 32 + t) * 17 + b] + red[(1 * 32 + t) * 17 + b]
                    + red[(2 * 32 + t) * 17 + b] + red[(3 * 32 + t) * 17 + b];
            // column-major partials: part[col][slice], col = b*32 + (j*16+o)
            part[((size_t)b * 32 + t) * NSLICE + slice] = s;
        }
    }
}

// Reduce partials -> s[b,j,o], squash -> v. 32 blocks = one per (b,j).
// PASS 0: scale 0.5 (uniform softmax), write v0
// PASS 1: write v0+v1 (logits linear in accumulated v)
// PASS 2: write final v
template<int PASS>
__global__ __launch_bounds__(256) void caps_reduce(
    const float* __restrict__ part, const float* __restrict__ vprev,
    float* __restrict__ vout)
{
    const int blk = blockIdx.x;   // b*2 + j
    const int b = blk >> 1, j = blk & 1;
    const int t = threadIdx.x;
    const int o = t & 15;
    const int ch = t >> 4;
    const size_t base = ((size_t)b * 32 + j * 16 + o) * NSLICE;
    float s = 0.f;
    for (int g = ch; g < NSLICE; g += 16) s += part[base + g];
    __shared__ float red[256];
    red[t] = s;
    __syncthreads();
    if (t < 16) {
        float sv = 0.f;
        #pragma unroll
        for (int c = 0; c < 16; ++c) sv += red[c * 16 + t];
        if (PASS == 0) sv *= 0.5f;
        float sq = sv * sv;
        sq += __shfl_xor(sq, 1);
        sq += __shfl_xor(sq, 2);
        sq += __shfl_xor(sq, 4);
        sq += __shfl_xor(sq, 8);
        const float sn = sq;
        float v = sv * sn / ((1.f + sn) * sqrtf(sn + 1e-7f));
        if (PASS == 1) v += vprev[b * 32 + j * 16 + o];
        vout[b * 32 + j * 16 + o] = v;
    }
}

extern "C" void kernel_launch(void* const* d_in, const int* in_sizes, int n_in,
                              void* d_out, int out_size, void* d_ws, size_t ws_size,
                              hipStream_t stream) {
    const float* x = (const float*)d_in[0];
    const float* W = (const float*)d_in[1];
    float* out = (float*)d_out;

    float* part = (float*)d_ws;                       // 512*1428 floats = 2.9MB
    float* v0   = part + (size_t)512 * NSLICE;        // 512
    float* vsum = v0 + 512;                           // 512

    caps_pass<0><<<NSLICE, TPB, 0, stream>>>(x, W, nullptr, part);
    caps_reduce<0><<<32, 256, 0, stream>>>(part, nullptr, v0);
    caps_pass<1><<<NSLICE, TPB, 0, stream>>>(x, W, v0, part);
    caps_reduce<1><<<32, 256, 0, stream>>>(part, v0, vsum);
    caps_pass<2><<<NSLICE, TPB, 0, stream>>>(x, W, vsum, part);
    caps_reduce<2><<<32, 256, 0, stream>>>(part, nullptr, out);
}